// Round 9
// baseline (212.257 us; speedup 1.0000x reference)
//
#include <hip/hip_runtime.h>
#include <stdint.h>

typedef short s16x8 __attribute__((ext_vector_type(8)));
typedef float f32x4 __attribute__((ext_vector_type(4)));
typedef unsigned short u16;
typedef unsigned int u32;

__device__ __forceinline__ float bf2f(u16 u) {
  union { u32 i; float f; } v; v.i = ((u32)u) << 16; return v.f;
}
__device__ __forceinline__ u16 f2bf(float f) {  // round-to-nearest-even
  union { float f; u32 i; } v; v.f = f;
  u32 i = v.i;
  return (u16)((i + 0x7fffu + ((i >> 16) & 1u)) >> 16);
}
__device__ __forceinline__ u16 f2bf_fast(float f) {  // round-half-up
  union { float f; u32 i; } v; v.f = f;
  return (u16)((v.i + 0x8000u) >> 16);
}

__device__ __forceinline__ s16x8 load8(const void* p, size_t idx, int isf32) {
  s16x8 r;
  if (isf32) {
    const float* f = (const float*)p + idx;
    f32x4 a = *(const f32x4*)f;
    f32x4 b = *(const f32x4*)(f + 4);
#pragma unroll
    for (int j = 0; j < 4; j++) {
      r[j] = (short)f2bf(a[j]);
      r[4 + j] = (short)f2bf(b[j]);
    }
  } else {
    r = *(const s16x8*)((const u16*)p + idx);
  }
  return r;
}
__device__ __forceinline__ float loadf(const void* p, size_t idx, int isf32) {
  return isf32 ? ((const float*)p)[idx] : bf2f(((const u16*)p)[idx]);
}

// async global->LDS 16B/lane; LDS dest = wave-uniform base + lane*16.
__device__ __forceinline__ void cp16(const u16* g, u16* l) {
  __builtin_amdgcn_global_load_lds(
      (const __attribute__((address_space(1))) u32*)g,
      (__attribute__((address_space(3))) u32*)l, 16, 0, 0);
}

// RoPE on a 4-pair bf16 fragment with fp32 cos/sin.
__device__ __forceinline__ s16x8 rope8(s16x8 x, const float* c, const float* s) {
  s16x8 out;
#pragma unroll
  for (int j = 0; j < 4; j++) {
    float x1 = bf2f((u16)x[2 * j]);
    float x2 = bf2f((u16)x[2 * j + 1]);
    out[2 * j] = (short)f2bf(x1 * c[j] - x2 * s[j]);
    out[2 * j + 1] = (short)f2bf(x1 * s[j] + x2 * c[j]);
  }
  return out;
}

// ---------------------------------------------------------------------------
// Dtype detector (R3-proven): flags[0]=1 if inputs fp32, flags[1]=0.
// ---------------------------------------------------------------------------
__global__ void detect_dtype(const u16* __restrict__ x, int* __restrict__ flags) {
  int cnt = 0;
  for (int i = threadIdx.x; i < 4096; i += 64) {
    int e = (x[i] >> 7) & 0xFF;
    if (e >= 0xF0) cnt++;
  }
  unsigned long long any = __ballot(cnt > 0);
  if (threadIdx.x == 0) {
    flags[0] = (any != 0ull) ? 1 : 0;
    flags[1] = 0;
  }
}

__global__ __launch_bounds__(256) void convert_x(const void* __restrict__ x,
                                                 const int* __restrict__ fp,
                                                 u16* __restrict__ xb) {
  size_t i = ((size_t)blockIdx.x * 256 + threadIdx.x) * 8;
  *(s16x8*)(xb + i) = load8(x, i, *fp);
}

// ---------------------------------------------------------------------------
// Fused weight transposes (R8-proven): Wqkv->WqkvT, Wproj->WprojT.
// ---------------------------------------------------------------------------
__global__ __launch_bounds__(256) void transposeW2(
    const void* __restrict__ Wqkv, const void* __restrict__ Wproj,
    const int* __restrict__ fp, u16* __restrict__ WqkvT,
    u16* __restrict__ WprojT) {
  __shared__ u32 tile32[32 * 66];
  const int f = *fp;
  const int tid = threadIdx.x;
  const int bx = blockIdx.x;
  const void* W;
  u16* WT;
  int N, nb;
  if (bx < 48) { W = Wqkv; WT = WqkvT; N = 3072; nb = bx * 64; }
  else         { W = Wproj; WT = WprojT; N = 1024; nb = (bx - 48) * 64; }
  const int kb = blockIdx.y * 64;  // K = 1024
  {
    int a = tid >> 3, c8 = tid & 7;
    s16x8 r0 = load8(W, (size_t)(kb + 2 * a) * N + nb + c8 * 8, f);
    s16x8 r1 = load8(W, (size_t)(kb + 2 * a + 1) * N + nb + c8 * 8, f);
#pragma unroll
    for (int j = 0; j < 8; j++)
      tile32[a * 66 + c8 * 8 + j] = (u32)(u16)r0[j] | ((u32)(u16)r1[j] << 16);
  }
  __syncthreads();
#pragma unroll
  for (int i = 0; i < 2; i++) {
    int idx = tid + i * 256;
    int n = idx >> 3, c8 = idx & 7;
    s16x8 v;
#pragma unroll
    for (int w = 0; w < 4; w++) {
      u32 pk = tile32[(c8 * 4 + w) * 66 + n];
      v[2 * w] = (short)(u16)(pk & 0xFFFF);
      v[2 * w + 1] = (short)(u16)(pk >> 16);
    }
    *(s16x8*)(WT + (size_t)(nb + n) * 1024 + kb + c8 * 8) = v;
  }
}

// ---------------------------------------------------------------------------
// Postproc: per (tb=64 rows, bh): (a) RoPE Q,K in place (coalesced, f32x4
// cos/sin), (b) V transpose -> vT[bh*64+d][2048] (R6-proven u32-packed).
// ---------------------------------------------------------------------------
__global__ __launch_bounds__(256) void postproc(u16* __restrict__ qkv,
                                                u16* __restrict__ vT,
                                                const void* __restrict__ cost,
                                                const void* __restrict__ sint,
                                                const int* __restrict__ fp) {
  __shared__ u32 tile32[64 * 33];
  const int f = *fp;
  const int tid = threadIdx.x;
  const int tb = blockIdx.x * 64, bh = blockIdx.y;
  const int b = bh >> 4, h = bh & 15;

  {  // V transpose load phase
    int a = tid >> 3, c8 = tid & 7;
    const u16* base = qkv + (size_t)(b * 2048 + tb + 2 * a) * 3072 + 2048 + h * 64;
    s16x8 r0 = *(const s16x8*)(base + c8 * 8);
    s16x8 r1 = *(const s16x8*)(base + 3072 + c8 * 8);
#pragma unroll
    for (int j = 0; j < 8; j++)
      tile32[(c8 * 8 + j) * 33 + a] = (u32)(u16)r0[j] | ((u32)(u16)r1[j] << 16);
  }

  // RoPE Q and K slices [64 rows x 64 cols], in place (no LDS dependency)
#pragma unroll
  for (int g = 0; g < 2; g++) {
    int gi = tid + g * 256;          // 0..511
    int row = gi >> 3, c8 = gi & 7;  // 64 rows x 8 col-groups
    int t = tb + row;
    size_t base = (size_t)(b * 2048 + t) * 3072 + h * 64 + c8 * 8;
    float cc[4], ss[4];
    if (f) {
      f32x4 cv = *(const f32x4*)((const float*)cost + (size_t)t * 32 + c8 * 4);
      f32x4 sv = *(const f32x4*)((const float*)sint + (size_t)t * 32 + c8 * 4);
#pragma unroll
      for (int k = 0; k < 4; k++) { cc[k] = cv[k]; ss[k] = sv[k]; }
    } else {
#pragma unroll
      for (int k = 0; k < 4; k++) {
        cc[k] = bf2f(((const u16*)cost)[(size_t)t * 32 + c8 * 4 + k]);
        ss[k] = bf2f(((const u16*)sint)[(size_t)t * 32 + c8 * 4 + k]);
      }
    }
    s16x8 q = *(const s16x8*)(qkv + base);
    *(s16x8*)(qkv + base) = rope8(q, cc, ss);
    s16x8 kk = *(const s16x8*)(qkv + base + 1024);
    *(s16x8*)(qkv + base + 1024) = rope8(kk, cc, ss);
  }

  __syncthreads();
#pragma unroll
  for (int i = 0; i < 2; i++) {  // V transpose store phase
    int idx = tid + i * 256;
    int d = idx >> 3, c8 = idx & 7;
    s16x8 v;
#pragma unroll
    for (int w = 0; w < 4; w++) {
      u32 pk = tile32[d * 33 + c8 * 4 + w];
      v[2 * w] = (short)(u16)(pk & 0xFFFF);
      v[2 * w + 1] = (short)(u16)(pk >> 16);
    }
    *(s16x8*)(vT + ((size_t)bh * 64 + d) * 2048 + tb + c8 * 8) = v;
  }
}

// ---------------------------------------------------------------------------
// m97-style GEMM: C = A[M,K(lda)] @ Bt[N,K]^T + bias. 128 x NT tile, BK=32.
// bf16 outputs go through an LDS C-stage for fully-coalesced 64B/lane
// stores (two 64-row halves reusing the staging LDS). outF&&fp32: direct
// fp32 stores (already 64B-segment coalesced).
// ---------------------------------------------------------------------------
template <int NT>
__global__ __launch_bounds__(256) void gemm_bt(
    const u16* __restrict__ A, int lda, const u16* __restrict__ Bt,
    const void* __restrict__ bias, const int* __restrict__ fI32,
    void* __restrict__ C, int outF, int N, int K) {
  constexpr int NTW = NT / 32;
  constexpr int CS = NT + 4;  // C-stage stride (quad-spread banks)
  constexpr int STAGE = 128 * 32 + NT * 32;
  constexpr int SMSZ = (STAGE > 64 * CS) ? STAGE : 64 * CS;
  __shared__ __attribute__((aligned(16))) u16 SMEM[SMSZ];
  u16* As = SMEM;
  u16* Bs = SMEM + 128 * 32;
  const int inf32 = *fI32;
  const int tid = threadIdx.x;
  const int wave = tid >> 6, lane = tid & 63, quad = lane >> 4, l16 = lane & 15;
  const int m0 = blockIdx.y * 128, n0 = blockIdx.x * NT;
  const int wm = (wave & 1) * 64, wn = (wave >> 1) * (NT / 2);
  const int lr = lane >> 2, lk = (lane & 3) * 8;
  f32x4 acc[4][NTW];
#pragma unroll
  for (int i = 0; i < 4; i++)
#pragma unroll
    for (int j = 0; j < NTW; j++) acc[i][j] = (f32x4){0.f, 0.f, 0.f, 0.f};

  const u16* aP = A + (size_t)(m0 + wave * 32 + lr) * lda + lk;
  const u16* bP = Bt + (size_t)(n0 + wave * (NT / 4) + lr) * K + lk;
  u16* asl = As + wave * 32 * 32;
  u16* bsl = Bs + wave * (NT / 4) * 32;

  for (int kb = 0; kb < K; kb += 32) {
    __syncthreads();
    cp16(aP + kb, asl);
    cp16(aP + kb + (size_t)16 * lda, asl + 16 * 32);
#pragma unroll
    for (int i = 0; i < NT / 64; i++)
      cp16(bP + kb + (size_t)(16 * i) * K, bsl + i * 16 * 32);
    __syncthreads();
    s16x8 af[4], bfr[NTW];
#pragma unroll
    for (int t = 0; t < 4; t++)
      af[t] = *(const s16x8*)(As + (wm + t * 16 + l16) * 32 + quad * 8);
#pragma unroll
    for (int t = 0; t < NTW; t++)
      bfr[t] = *(const s16x8*)(Bs + (wn + t * 16 + l16) * 32 + quad * 8);
#pragma unroll
    for (int mt = 0; mt < 4; mt++)
#pragma unroll
      for (int nt = 0; nt < NTW; nt++)
        acc[mt][nt] = __builtin_amdgcn_mfma_f32_16x16x32_bf16(
            af[mt], bfr[nt], acc[mt][nt], 0, 0, 0);
  }

  float bv[NTW];
#pragma unroll
  for (int nt = 0; nt < NTW; nt++)
    bv[nt] = loadf(bias, n0 + wn + nt * 16 + l16, inf32);

  if (outF && inf32) {  // final fp32 output: 64B segments, direct
#pragma unroll
    for (int nt = 0; nt < NTW; nt++) {
      int col = n0 + wn + nt * 16 + l16;
#pragma unroll
      for (int mt = 0; mt < 4; mt++)
#pragma unroll
        for (int r = 0; r < 4; r++) {
          int row = m0 + wm + mt * 16 + quad * 4 + r;
          ((float*)C)[(size_t)row * N + col] = acc[mt][nt][r] + bv[nt];
        }
    }
    return;
  }

  // bf16 output: LDS C-stage remap, two 64-row halves
  u16* Cs = SMEM;
#pragma unroll
  for (int half = 0; half < 2; half++) {
    __syncthreads();  // As/Bs reads (half0) / prior store reads (half1) done
    if ((wave & 1) == half) {
#pragma unroll
      for (int mt = 0; mt < 4; mt++)
#pragma unroll
        for (int nt = 0; nt < NTW; nt++)
#pragma unroll
          for (int r = 0; r < 4; r++)
            Cs[(mt * 16 + quad * 4 + r) * CS + wn + nt * 16 + l16] =
                f2bf(acc[mt][nt][r] + bv[nt]);
    }
    __syncthreads();
    int row = tid >> 2, cg = tid & 3;       // 64 rows x 4 col-groups
    int colbase = cg * (NT / 4);            // NT/4 cols per thread
    u16* gout = (u16*)C + (size_t)(m0 + half * 64 + row) * N + n0 + colbase;
    const u16* lsrc = Cs + row * CS + colbase;
#pragma unroll
    for (int k2 = 0; k2 < NT / 32; k2++)
      *(s16x8*)(gout + k2 * 8) = *(const s16x8*)(lsrc + k2 * 8);
  }
}

// ---------------------------------------------------------------------------
// Causal flash attention v4 (R8-proven). 512 thr = 8 waves, 16 Q rows/wave,
// 128-row blocks, 64-key chunks, fixed-base softmax + deferred l-reduction,
// K/V register-prefetch. y -> dead V-columns of qkv. Heavy/light CU pairing.
// ---------------------------------------------------------------------------
__global__ __launch_bounds__(512) void attn_kernel(u16* qkv,
                                                   const u16* __restrict__ vT) {
  __shared__ __attribute__((aligned(16))) u16 Ks[64 * 72];
  __shared__ __attribute__((aligned(16))) u16 Vt[64 * 72];
  __shared__ __attribute__((aligned(16))) u16 Pl[8][16 * 72];
  const int tid = threadIdx.x;
  const int wave = tid >> 6, lane = tid & 63, quad = lane >> 4, l16 = lane & 15;
  const int cu = blockIdx.x & 255, round = blockIdx.x >> 8;
  const int p = cu >> 5, bh = cu & 31;
  const int qt = round ? p : 15 - p;  // heavy first
  const int h = bh & 15;
  const size_t rb = (size_t)(bh >> 4) * 2048;
  const int qb = qt * 128;
  const float SCALE = 0.18033688011112042f;  // 0.125 * log2(e)

  s16x8 qa0, qa1;
  {
    const u16* qp = qkv + (rb + qb + wave * 16 + l16) * 3072 + h * 64;
    qa0 = *(const s16x8*)(qp + quad * 8);
    qa1 = *(const s16x8*)(qp + 32 + quad * 8);
  }

  f32x4 o[4];
  float l_r[4] = {0.f, 0.f, 0.f, 0.f};
#pragma unroll
  for (int i = 0; i < 4; i++) o[i] = (f32x4){0.f, 0.f, 0.f, 0.f};

  const int nchunks = 2 * qt + 2;
  const int srow = tid >> 3, sc8 = tid & 7;
  s16x8 kr, vr;
  {
    kr = *(const s16x8*)(qkv + (rb + srow) * 3072 + 1024 + h * 64 + sc8 * 8);
    vr = *(const s16x8*)(vT + ((size_t)bh * 64 + srow) * 2048 + sc8 * 8);
  }

  for (int c = 0; c < nchunks; c++) {
    const int sb = c * 64;
    __syncthreads();
    *(s16x8*)(Ks + srow * 72 + sc8 * 8) = kr;
    *(s16x8*)(Vt + srow * 72 + sc8 * 8) = vr;
    __syncthreads();
    if (c + 1 < nchunks) {
      const int nb = sb + 64;
      kr = *(const s16x8*)(qkv + (rb + nb + srow) * 3072 + 1024 + h * 64 +
                           sc8 * 8);
      vr = *(const s16x8*)(vT + ((size_t)bh * 64 + srow) * 2048 + nb + sc8 * 8);
    }

    if (sb > qb + wave * 16 + 15) continue;

    f32x4 S[4];
#pragma unroll
    for (int kf = 0; kf < 4; kf++) {
      s16x8 k0 = *(const s16x8*)(Ks + (kf * 16 + l16) * 72 + quad * 8);
      s16x8 k1 = *(const s16x8*)(Ks + (kf * 16 + l16) * 72 + 32 + quad * 8);
      f32x4 a = (f32x4){0.f, 0.f, 0.f, 0.f};
      a = __builtin_amdgcn_mfma_f32_16x16x32_bf16(qa0, k0, a, 0, 0, 0);
      a = __builtin_amdgcn_mfma_f32_16x16x32_bf16(qa1, k1, a, 0, 0, 0);
      S[kf] = a;
    }

    u16* P = Pl[wave];
    const int mq = qb + wave * 16;
    const bool needMask = (sb + 63) > mq;
#pragma unroll
    for (int r = 0; r < 4; r++) {
      const int qi = mq + quad * 4 + r;
#pragma unroll
      for (int kf = 0; kf < 4; kf++) {
        float pv = __builtin_amdgcn_exp2f(S[kf][r] * SCALE);
        if (needMask) pv = ((sb + kf * 16 + l16) <= qi) ? pv : 0.f;
        l_r[r] += pv;
        P[(quad * 4 + r) * 72 + kf * 16 + l16] = f2bf_fast(pv);
      }
    }
    asm volatile("s_waitcnt lgkmcnt(0)" ::: "memory");
    s16x8 pa0 = *(const s16x8*)(P + l16 * 72 + quad * 8);
    s16x8 pa1 = *(const s16x8*)(P + l16 * 72 + 32 + quad * 8);

#pragma unroll
    for (int dt = 0; dt < 4; dt++) {
      s16x8 vb0 = *(const s16x8*)(Vt + (dt * 16 + l16) * 72 + quad * 8);
      s16x8 vb1 = *(const s16x8*)(Vt + (dt * 16 + l16) * 72 + 32 + quad * 8);
      o[dt] = __builtin_amdgcn_mfma_f32_16x16x32_bf16(pa0, vb0, o[dt], 0, 0, 0);
      o[dt] = __builtin_amdgcn_mfma_f32_16x16x32_bf16(pa1, vb1, o[dt], 0, 0, 0);
    }
  }

  float inv[4];
#pragma unroll
  for (int r = 0; r < 4; r++) {
    float rs = l_r[r];
#pragma unroll
    for (int off = 8; off; off >>= 1) rs += __shfl_xor(rs, off);
    inv[r] = 1.0f / fmaxf(rs, 1e-30f);
  }
#pragma unroll
  for (int dt = 0; dt < 4; dt++)
#pragma unroll
    for (int r = 0; r < 4; r++)
      qkv[(rb + qb + wave * 16 + quad * 4 + r) * 3072 + 2048 + h * 64 +
          dt * 16 + l16] = f2bf(o[dt][r] * inv[r]);
}

extern "C" void kernel_launch(void* const* d_in, const int* in_sizes, int n_in,
                              void* d_out, int out_size, void* d_ws,
                              size_t ws_size, hipStream_t stream) {
  const void* x = d_in[0];
  const void* Wqkv = d_in[1];
  const void* bqkv = d_in[2];
  const void* Wproj = d_in[3];
  const void* bproj = d_in[4];
  const void* cost = d_in[5];
  const void* sint = d_in[6];

  int* flags = (int*)d_ws;
  u16* WqkvT = (u16*)d_ws + 128;               // [3072][1024] bf16
  u16* WprojT = WqkvT + (size_t)3072 * 1024;   // [1024][1024] bf16
  u16* qkv = WprojT + (size_t)1024 * 1024;     // [4096][3072] bf16
  u16* yb = qkv + 2048;                        // y = V-columns of qkv
  u16* xb = (u16*)d_out;                       // bf16 x scratch (lower half)
  u16* vT = (u16*)d_out + (size_t)4096 * 1024; // V^T (upper half)

  detect_dtype<<<1, 64, 0, stream>>>((const u16*)x, flags);
  convert_x<<<2048, 256, 0, stream>>>(x, flags, xb);
  transposeW2<<<dim3(64, 16), 256, 0, stream>>>(Wqkv, Wproj, flags, WqkvT,
                                                WprojT);
  gemm_bt<128><<<dim3(24, 32), 256, 0, stream>>>(xb, 1024, WqkvT, bqkv, flags,
                                                 qkv, 0, 3072, 1024);
  postproc<<<dim3(32, 32), 256, 0, stream>>>(qkv, vT, cost, sint, flags);
  attn_kernel<<<512, 512, 0, stream>>>(qkv, vT);
  gemm_bt<64><<<dim3(16, 32), 256, 0, stream>>>(yb, 3072, WprojT, bproj, flags,
                                                d_out, 1, 1024, 1024);
}